// Round 10
// baseline (652.714 us; speedup 1.0000x reference)
//
#include <hip/hip_runtime.h>
#include <hip/hip_bf16.h>
#include <math.h>

#define L_SEQ 2048
#define S_SEQ 2048
#define N_B 2
#define E_DIM 512
#define H_HEADS 8
#define D_HEAD 64
#define M_ROWS (L_SEQ * N_B)
#define BH (H_HEADS * N_B)   // batch index = h*N_B + n (matches attn_weights reshape (H*N, L, S))

typedef __attribute__((ext_vector_type(8))) short bf16x8;
typedef __attribute__((ext_vector_type(4))) float f32x4;

#define MFMA(a, b, c) __builtin_amdgcn_mfma_f32_16x16x32_bf16((a), (b), (c), 0, 0, 0)
// Verified layouts (learn_hip m89/m91):
//   A-frag: A[m = lane&15][k = (lane>>4)*8 + j]   (8 contiguous k per lane)
//   B-frag: B[k = (lane>>4)*8 + j][n = lane&15]   (read from row-major Bt[n][k])
//   C/D   : col = lane&15, row = (lane>>4)*4 + reg

__device__ __forceinline__ short f2bf(float v) {
    union { __hip_bfloat16 h; short s; } u;
    u.h = __float2bfloat16(v);
    return u.s;
}
__device__ __forceinline__ float bf2f(short s) {
    union { __hip_bfloat16 h; short t; } u;
    u.t = s;
    return __bfloat162float(u.h);
}
__device__ __forceinline__ void cvt8_hl(const float4& a, const float4& b, bf16x8& h, bf16x8& l) {
    float v[8] = {a.x, a.y, a.z, a.w, b.x, b.y, b.z, b.w};
#pragma unroll
    for (int i = 0; i < 8; ++i) {
        short hh = f2bf(v[i]);
        h[i] = hh;
        l[i] = f2bf(v[i] - bf2f(hh));
    }
}
__device__ __forceinline__ bf16x8 cvt8_h(const float4& a, const float4& b) {
    float v[8] = {a.x, a.y, a.z, a.w, b.x, b.y, b.z, b.w};
    bf16x8 h;
#pragma unroll
    for (int i = 0; i < 8; ++i) h[i] = f2bf(v[i]);
    return h;
}

// ---------------------------------------------------------------------------
// Deterministic workspace init: zero the 28 MB of d_ws we use so every launch
// starts from identical state regardless of harness poison.
// ---------------------------------------------------------------------------
__global__ __launch_bounds__(256) void fill_kernel(float4* __restrict__ p, int n4) {
    const float4 z = {0.f, 0.f, 0.f, 0.f};
    for (int i = blockIdx.x * 256 + threadIdx.x; i < n4; i += gridDim.x * 256) p[i] = z;
}

// ---------------------------------------------------------------------------
// Streaming fp32 -> split-bf16 (hi + lo residual). Done ONCE per tensor:
// removes the 8-64x redundant per-tile conversions R0's proj did in-block.
// Produces bit-identical hi/lo to the in-kernel cvt (same cvt8_hl).
// ---------------------------------------------------------------------------
__global__ __launch_bounds__(256) void split_kernel(const float* __restrict__ in,
                                                    short* __restrict__ hi,
                                                    short* __restrict__ lo, int n8) {
    const int i = blockIdx.x * 256 + threadIdx.x;
    if (i >= n8) return;
    const float4* p = (const float4*)(in + (size_t)i * 8);
    bf16x8 h, l;
    cvt8_hl(p[0], p[1], h, l);
    *(bf16x8*)(hi + (size_t)i * 8) = h;
    *(bf16x8*)(lo + (size_t)i * 8) = l;
}

// ---------------------------------------------------------------------------
// QKV projection: Y = X @ W^T + b, split-bf16 (hi/lo, 3 MFMAs = same op order
// as R0). Operands are PRE-SPLIT bf16 in row-major [row][k] layout, which IS
// the MFMA fragment layout -> direct global loads, no LDS, no barriers.
// 64x64 tile, 256 threads (4 waves, wave = 16 M-rows). Plain blockIdx (no
// swizzle). Output: per-batch [bh = h*2+n][seq][64] bf16 hi (and lo if
// writeLo). Math is element-for-element identical to R0's proj_qkv_kernel.
// ---------------------------------------------------------------------------
__global__ __launch_bounds__(256) void proj_kernel(
    const short* __restrict__ Xh, const short* __restrict__ Xl,
    const short* __restrict__ Wh, const short* __restrict__ Wl,
    const float* __restrict__ bias, short* __restrict__ outH,
    short* __restrict__ outL, int writeLo) {
    const int bn = blockIdx.x * 64;
    const int bm = blockIdx.y * 64;
    const int tid = threadIdx.x;
    const int wave = tid >> 6, lane = tid & 63;
    const int m16 = lane & 15, q = lane >> 4;

    const short* pAh = Xh + (size_t)(bm + wave * 16 + m16) * E_DIM;
    const short* pAl = Xl + (size_t)(bm + wave * 16 + m16) * E_DIM;

    f32x4 acc[4] = {};
    for (int k0 = 0; k0 < E_DIM; k0 += 32) {
        const bf16x8 ah = *(const bf16x8*)(pAh + k0 + q * 8);
        const bf16x8 al = *(const bf16x8*)(pAl + k0 + q * 8);
#pragma unroll
        for (int j = 0; j < 4; ++j) {
            const size_t bo = (size_t)(bn + j * 16 + m16) * E_DIM + k0 + q * 8;
            const bf16x8 bh_ = *(const bf16x8*)(Wh + bo);
            const bf16x8 bl_ = *(const bf16x8*)(Wl + bo);
            acc[j] = MFMA(ah, bh_, acc[j]);
            acc[j] = MFMA(ah, bl_, acc[j]);
            acc[j] = MFMA(al, bh_, acc[j]);
        }
    }

#pragma unroll
    for (int j = 0; j < 4; ++j) {
        const int e = bn + j * 16 + m16;
        const int h = e >> 6, d = e & 63;
        const float be = bias[e];
#pragma unroll
        for (int r = 0; r < 4; ++r) {
            const int row = bm + wave * 16 + q * 4 + r;
            const int l = row >> 1, nb = row & 1;
            const float v = acc[j][r] + be;
            const size_t idx = ((size_t)(h * 2 + nb) * L_SEQ + l) * D_HEAD + d;
            const short hi = f2bf(v);
            outH[idx] = hi;
            if (writeLo) outL[idx] = f2bf(v - bf2f(hi));
        }
    }
}

// ---------------------------------------------------------------------------
// V transpose: Vb [bh][s][64] bf16 -> Vt [bh][64][s] bf16 (k-contiguous B-frags)
// ---------------------------------------------------------------------------
__global__ __launch_bounds__(256) void vtrans_kernel(const short* __restrict__ Vb,
                                                     short* __restrict__ Vt) {
    __shared__ short tile[64][65];
    const int s0 = blockIdx.x * 64;
    const int bh = blockIdx.y;
    const int t = threadIdx.x;
    const int r = t >> 2, seg = (t & 3) * 16;
    const bf16x8* p = (const bf16x8*)(Vb + ((size_t)bh * S_SEQ + s0 + r) * D_HEAD + seg);
    bf16x8 v0 = p[0], v1 = p[1];
#pragma unroll
    for (int i = 0; i < 8; ++i) {
        tile[r][seg + i] = v0[i];
        tile[r][seg + 8 + i] = v1[i];
    }
    __syncthreads();
    bf16x8 o0, o1;
#pragma unroll
    for (int i = 0; i < 8; ++i) {
        o0[i] = tile[seg + i][r];
        o1[i] = tile[seg + 8 + i][r];
    }
    bf16x8* po = (bf16x8*)(Vt + ((size_t)bh * D_HEAD + r) * S_SEQ + s0 + seg);
    po[0] = o0;
    po[1] = o1;
}

// ---------------------------------------------------------------------------
// Fused scores + bias + softmax + PV — VERBATIM the verified round-0 kernel
// (all barriers, no block swizzle). Block = (bh, 16 L-rows), 512 thr = 8 waves.
// ---------------------------------------------------------------------------
__global__ __launch_bounds__(512) void scores_pv_kernel(
    const short* __restrict__ Qh, const short* __restrict__ Ql,
    const short* __restrict__ Kh, const short* __restrict__ Kl,
    const short* __restrict__ Vt, const float* __restrict__ bias,
    float* __restrict__ wout, short* __restrict__ ctx) {
    const int bh = blockIdx.y;
    const int l0 = blockIdx.x * 16;
    const int tid = threadIdx.x;
    const int wave = tid >> 6, lane = tid & 63;
    const int m16 = lane & 15, q = lane >> 4;
    const int sbase = wave * 256;

    __shared__ float LMAX[8][16], LSUM[8][16];
    __shared__ __align__(16) float SM_T[8][32][17];   // per-wave P transpose tile
    __shared__ __align__(16) float OB[8][16][65];     // partial O per wave

    // ---- Phase 1: QK^T + bias ----
    const size_t qoff = ((size_t)bh * L_SEQ + l0 + m16) * D_HEAD;
    bf16x8 aH[2], aL[2];
#pragma unroll
    for (int ks = 0; ks < 2; ++ks) {
        aH[ks] = *(const bf16x8*)(Qh + qoff + ks * 32 + q * 8);
        aL[ks] = *(const bf16x8*)(Ql + qoff + ks * 32 + q * 8);
    }

    f32x4 C[16] = {};
#pragma unroll
    for (int t = 0; t < 16; ++t) {
        const size_t koff = ((size_t)bh * S_SEQ + sbase + t * 16 + m16) * D_HEAD;
#pragma unroll
        for (int ks = 0; ks < 2; ++ks) {
            const bf16x8 kh = *(const bf16x8*)(Kh + koff + ks * 32 + q * 8);
            const bf16x8 kl = *(const bf16x8*)(Kl + koff + ks * 32 + q * 8);
            C[t] = MFMA(aH[ks], kh, C[t]);
            C[t] = MFMA(aH[ks], kl, C[t]);
            C[t] = MFMA(aL[ks], kh, C[t]);
        }
    }

    const int row0 = l0 + q * 4;
#pragma unroll
    for (int r = 0; r < 4; ++r) {
        const float* brow = bias + (size_t)(row0 + r) * S_SEQ + sbase + m16;
#pragma unroll
        for (int t = 0; t < 16; ++t) C[t][r] = C[t][r] * 0.125f + brow[t * 16];
    }

    // ---- softmax (exact, 2-pass over registers) ----
    float mx[4] = {-INFINITY, -INFINITY, -INFINITY, -INFINITY};
#pragma unroll
    for (int t = 0; t < 16; ++t)
#pragma unroll
        for (int r = 0; r < 4; ++r) mx[r] = fmaxf(mx[r], C[t][r]);
#pragma unroll
    for (int d = 1; d < 16; d <<= 1)
#pragma unroll
        for (int r = 0; r < 4; ++r) mx[r] = fmaxf(mx[r], __shfl_xor(mx[r], d, 64));
    if (m16 == 0) {
#pragma unroll
        for (int r = 0; r < 4; ++r) LMAX[wave][q * 4 + r] = mx[r];
    }
    __syncthreads();
    float M[4];
#pragma unroll
    for (int r = 0; r < 4; ++r) {
        float v = -INFINITY;
#pragma unroll
        for (int w = 0; w < 8; ++w) v = fmaxf(v, LMAX[w][q * 4 + r]);
        M[r] = v;
    }

    float sm[4] = {};
#pragma unroll
    for (int t = 0; t < 16; ++t)
#pragma unroll
        for (int r = 0; r < 4; ++r) {
            const float e = __expf(C[t][r] - M[r]);
            C[t][r] = e;
            sm[r] += e;
        }
#pragma unroll
    for (int d = 1; d < 16; d <<= 1)
#pragma unroll
        for (int r = 0; r < 4; ++r) sm[r] += __shfl_xor(sm[r], d, 64);
    if (m16 == 0) {
#pragma unroll
        for (int r = 0; r < 4; ++r) LSUM[wave][q * 4 + r] = sm[r];
    }
    __syncthreads();
#pragma unroll
    for (int r = 0; r < 4; ++r) {
        float s = 0.f;
#pragma unroll
        for (int w = 0; w < 8; ++w) s += LSUM[w][q * 4 + r];
        const float inv = 1.0f / s;
        float* orow = wout + ((size_t)bh * L_SEQ + row0 + r) * S_SEQ + sbase + m16;
#pragma unroll
        for (int t = 0; t < 16; ++t) {
            C[t][r] *= inv;
            orow[t * 16] = C[t][r];
        }
    }

    // ---- Phase 2: O = P @ V (per-wave strip), P via LDS transpose ----
    f32x4 O[4] = {};
    float (*T)[17] = SM_T[wave];
    for (int c = 0; c < 8; ++c) {
        __syncthreads();   // WAR: previous iteration's reads of T complete
#pragma unroll
        for (int r = 0; r < 4; ++r) {
            T[m16][q * 4 + r]      = C[2 * c][r];
            T[16 + m16][q * 4 + r] = C[2 * c + 1][r];
        }
        __syncthreads();
        bf16x8 a;
#pragma unroll
        for (int j = 0; j < 8; ++j) a[j] = f2bf(T[q * 8 + j][m16]);
        const int scol = sbase + c * 32;
#pragma unroll
        for (int j = 0; j < 4; ++j) {
            const bf16x8 b =
                *(const bf16x8*)(Vt + ((size_t)bh * D_HEAD + j * 16 + m16) * S_SEQ + scol + q * 8);
            O[j] = MFMA(a, b, O[j]);
        }
    }

    // ---- Phase 3: reduce partial O across waves, write ctx ----
    __syncthreads();
#pragma unroll
    for (int j = 0; j < 4; ++j)
#pragma unroll
        for (int r = 0; r < 4; ++r) OB[wave][q * 4 + r][j * 16 + m16] = O[j][r];
    __syncthreads();

    const int h = bh >> 1, n = bh & 1;
#pragma unroll
    for (int u = 0; u < 2; ++u) {
        const int idx = tid + u * 512;        // 0..1023 = 16 rows x 64 d
        const int row = idx >> 6, d = idx & 63;
        float s = 0.f;
#pragma unroll
        for (int w = 0; w < 8; ++w) s += OB[w][row][d];
        ctx[(size_t)((l0 + row) * N_B + n) * E_DIM + h * D_HEAD + d] = f2bf(s);
    }
}

// ---------------------------------------------------------------------------
// Output projection: out = ctx(bf16) @ Wo^T + bo, fp32 out — VERBATIM round-0.
// ---------------------------------------------------------------------------
__global__ __launch_bounds__(256) void oproj_kernel(const short* __restrict__ ctx,
                                                    const float* __restrict__ W,
                                                    const float* __restrict__ bias,
                                                    float* __restrict__ out) {
    __shared__ __align__(16) short Bh[64 * 40];
    const int bn = blockIdx.x * 64;
    const int bm = blockIdx.y * 64;
    const int tid = threadIdx.x;
    const int wave = tid >> 6, lane = tid & 63;
    const int m16 = lane & 15, q = lane >> 4;
    const int srow = tid >> 2, sk = (tid & 3) * 8;

    f32x4 acc[4] = {};
    for (int k0 = 0; k0 < E_DIM; k0 += 32) {
        {
            const float4* pb = (const float4*)(W + (size_t)(bn + srow) * E_DIM + k0 + sk);
            *(bf16x8*)&Bh[srow * 40 + sk] = cvt8_h(pb[0], pb[1]);
        }
        __syncthreads();
        const bf16x8 a = *(const bf16x8*)(ctx + (size_t)(bm + wave * 16 + m16) * E_DIM + k0 + q * 8);
#pragma unroll
        for (int j = 0; j < 4; ++j) {
            const bf16x8 b = *(const bf16x8*)&Bh[(j * 16 + m16) * 40 + q * 8];
            acc[j] = MFMA(a, b, acc[j]);
        }
        __syncthreads();
    }
#pragma unroll
    for (int j = 0; j < 4; ++j) {
        const int e = bn + j * 16 + m16;
        const float be = bias[e];
#pragma unroll
        for (int r = 0; r < 4; ++r)
            out[(size_t)(bm + wave * 16 + q * 4 + r) * E_DIM + e] = acc[j][r] + be;
    }
}

extern "C" void kernel_launch(void* const* d_in, const int* in_sizes, int n_in,
                              void* d_out, int out_size, void* d_ws, size_t ws_size,
                              hipStream_t stream) {
    const float* query = (const float*)d_in[0];
    const float* key   = (const float*)d_in[1];
    const float* value = (const float*)d_in[2];
    const float* bias  = (const float*)d_in[3];
    const float* Wq    = (const float*)d_in[4];
    const float* bq    = (const float*)d_in[5];
    const float* Wk    = (const float*)d_in[6];
    const float* bk    = (const float*)d_in[7];
    const float* Wv    = (const float*)d_in[8];
    const float* bv    = (const float*)d_in[9];
    const float* Wo    = (const float*)d_in[10];
    const float* bo    = (const float*)d_in[11];

    float* out0 = (float*)d_out;                       // attn_out (L,N,E) — write-only
    float* wgt  = out0 + (size_t)M_ROWS * E_DIM;       // attn_weights (BH,L,S) fp32 — write-only

    // ws: 7 x 4 MB bf16 buffers = 28 MB (identical footprint to round-0).
    // Slots 5/6 are time-shared: Xl/Xh during projections, Vt/ctx afterwards
    // (stream serialization makes the temporal reuse safe).
    short* wsS = (short*)d_ws;
    const size_t buf = (size_t)BH * L_SEQ * D_HEAD;    // 2,097,152 elems
    short* Qh  = wsS + 0 * buf;
    short* Ql  = wsS + 1 * buf;
    short* Kh  = wsS + 2 * buf;
    short* Kl  = wsS + 3 * buf;
    short* Vh  = wsS + 4 * buf;
    short* Vt  = wsS + 5 * buf;   short* Xl = Vt;      // Xl (projs) -> Vt (attn)
    short* ctx = wsS + 6 * buf;   short* Xh = ctx;     // Xh (projs) -> ctx (attn)

    // W-split scratch: last 1 MB of the 256 MB weights output, consumed
    // strictly BEFORE scores_pv overwrites the entire weights region.
    const size_t wb = (size_t)E_DIM * E_DIM;           // 262,144 elems (0.5 MB bf16)
    const size_t wgtElems = (size_t)BH * L_SEQ * S_SEQ;  // 67,108,864 floats
    short* WhT = (short*)wgt + 2 * wgtElems - 2 * wb;
    short* WlT = WhT + wb;

    const int nW8 = (int)(wb / 8);                     // 32768  -> 128 blocks
    const int nX8 = (int)((size_t)M_ROWS * E_DIM / 8); // 262144 -> 1024 blocks
    const dim3 gproj(E_DIM / 64, M_ROWS / 64);         // (8, 64)

    // Deterministic ws baseline every call (28 MB = 1,835,008 float4)
    fill_kernel<<<2048, 256, 0, stream>>>((float4*)d_ws, (int)(7 * buf * sizeof(short) / 16));

    // Q projection
    split_kernel<<<nX8 / 256, 256, 0, stream>>>(query, Xh, Xl, nX8);
    split_kernel<<<nW8 / 256, 256, 0, stream>>>(Wq, WhT, WlT, nW8);
    proj_kernel<<<gproj, 256, 0, stream>>>(Xh, Xl, WhT, WlT, bq, Qh, Ql, 1);
    // K projection
    split_kernel<<<nX8 / 256, 256, 0, stream>>>(key, Xh, Xl, nX8);
    split_kernel<<<nW8 / 256, 256, 0, stream>>>(Wk, WhT, WlT, nW8);
    proj_kernel<<<gproj, 256, 0, stream>>>(Xh, Xl, WhT, WlT, bk, Kh, Kl, 1);
    // V projection (lo not consumed: writeLo=0; dummy target never stored to)
    split_kernel<<<nX8 / 256, 256, 0, stream>>>(value, Xh, Xl, nX8);
    split_kernel<<<nW8 / 256, 256, 0, stream>>>(Wv, WhT, WlT, nW8);
    proj_kernel<<<gproj, 256, 0, stream>>>(Xh, Xl, WhT, WlT, bv, Vh, (short*)wgt, 0);

    vtrans_kernel<<<dim3(S_SEQ / 64, BH), 256, 0, stream>>>(Vh, Vt);

    scores_pv_kernel<<<dim3(L_SEQ / 16, BH), 512, 0, stream>>>(Qh, Ql, Kh, Kl, Vt, bias, wgt, ctx);

    oproj_kernel<<<gproj, 256, 0, stream>>>(ctx, Wo, bo, out0);
}

// Round 14
// 619.297 us; speedup vs baseline: 1.0540x; 1.0540x over previous
//
#include <hip/hip_runtime.h>
#include <hip/hip_bf16.h>
#include <math.h>

#define L_SEQ 2048
#define S_SEQ 2048
#define N_B 2
#define E_DIM 512
#define H_HEADS 8
#define D_HEAD 64
#define M_ROWS (L_SEQ * N_B)
#define BH (H_HEADS * N_B)   // batch index = h*N_B + n (matches attn_weights reshape (H*N, L, S))

typedef __attribute__((ext_vector_type(8))) short bf16x8;
typedef __attribute__((ext_vector_type(4))) float f32x4;

#define MFMA(a, b, c) __builtin_amdgcn_mfma_f32_16x16x32_bf16((a), (b), (c), 0, 0, 0)
// Verified layouts (learn_hip m89/m91):
//   A-frag: A[m = lane&15][k = (lane>>4)*8 + j]   (8 contiguous k per lane)
//   B-frag: B[k = (lane>>4)*8 + j][n = lane&15]   (read from row-major Bt[n][k])
//   C/D   : col = lane&15, row = (lane>>4)*4 + reg

__device__ __forceinline__ short f2bf(float v) {
    union { __hip_bfloat16 h; short s; } u;
    u.h = __float2bfloat16(v);
    return u.s;
}
__device__ __forceinline__ float bf2f(short s) {
    union { __hip_bfloat16 h; short t; } u;
    u.t = s;
    return __bfloat162float(u.h);
}
__device__ __forceinline__ void cvt8_hl(const float4& a, const float4& b, bf16x8& h, bf16x8& l) {
    float v[8] = {a.x, a.y, a.z, a.w, b.x, b.y, b.z, b.w};
#pragma unroll
    for (int i = 0; i < 8; ++i) {
        short hh = f2bf(v[i]);
        h[i] = hh;
        l[i] = f2bf(v[i] - bf2f(hh));
    }
}
__device__ __forceinline__ bf16x8 cvt8_h(const float4& a, const float4& b) {
    float v[8] = {a.x, a.y, a.z, a.w, b.x, b.y, b.z, b.w};
    bf16x8 h;
#pragma unroll
    for (int i = 0; i < 8; ++i) h[i] = f2bf(v[i]);
    return h;
}

// ---------------------------------------------------------------------------
// Deterministic workspace init (verbatim R0): zero the 28 MB of d_ws we use.
// ---------------------------------------------------------------------------
__global__ __launch_bounds__(256) void fill_kernel(float4* __restrict__ p, int n4) {
    const float4 z = {0.f, 0.f, 0.f, 0.f};
    for (int i = blockIdx.x * 256 + threadIdx.x; i < n4; i += gridDim.x * 256) p[i] = z;
}

// ---------------------------------------------------------------------------
// Streaming fp32 -> split-bf16, 3 tensors per launch (blockIdx.y selects).
// Body identical to the R10/R12-verified split_kernel.
// ---------------------------------------------------------------------------
__global__ __launch_bounds__(256) void split3_kernel(
    const float* __restrict__ in0, const float* __restrict__ in1, const float* __restrict__ in2,
    short* __restrict__ h0, short* __restrict__ l0,
    short* __restrict__ h1, short* __restrict__ l1,
    short* __restrict__ h2, short* __restrict__ l2, int n8) {
    const int z = blockIdx.y;
    const float* in = (z == 0) ? in0 : (z == 1) ? in1 : in2;
    short* hi = (z == 0) ? h0 : (z == 1) ? h1 : h2;
    short* lo = (z == 0) ? l0 : (z == 1) ? l1 : l2;
    const int i = blockIdx.x * 256 + threadIdx.x;
    if (i >= n8) return;
    const float4* p = (const float4*)(in + (size_t)i * 8);
    bf16x8 h, l;
    cvt8_hl(p[0], p[1], h, l);
    *(bf16x8*)(hi + (size_t)i * 8) = h;
    *(bf16x8*)(lo + (size_t)i * 8) = l;
}

// Single-tensor split (for Wo after scores_sm).
__global__ __launch_bounds__(256) void split_kernel(const float* __restrict__ in,
                                                    short* __restrict__ hi,
                                                    short* __restrict__ lo, int n8) {
    const int i = blockIdx.x * 256 + threadIdx.x;
    if (i >= n8) return;
    const float4* p = (const float4*)(in + (size_t)i * 8);
    bf16x8 h, l;
    cvt8_hl(p[0], p[1], h, l);
    *(bf16x8*)(hi + (size_t)i * 8) = h;
    *(bf16x8*)(lo + (size_t)i * 8) = l;
}

// ---------------------------------------------------------------------------
// QKV projection — R12-verified hybrid body (LDS-staged pre-split bf16, no
// in-loop cvt), ALL THREE projections in one launch: blockIdx.z selects the
// (X, W, bias, out) set. Grid 512 -> 1536 blocks = 6 blocks/CU, tripling the
// waves available to hide staging latency (R12 proj ran at 2 blocks/CU).
// Math is element-for-element identical to R12 (which matched R0 bit-exact).
// ---------------------------------------------------------------------------
__global__ __launch_bounds__(256) void proj_qkv3_kernel(
    const short* __restrict__ Xh0, const short* __restrict__ Xl0,
    const short* __restrict__ Xh1, const short* __restrict__ Xl1,
    const short* __restrict__ Xh2, const short* __restrict__ Xl2,
    const short* __restrict__ Wh0, const short* __restrict__ Wl0,
    const short* __restrict__ Wh1, const short* __restrict__ Wl1,
    const short* __restrict__ Wh2, const short* __restrict__ Wl2,
    const float* __restrict__ b0, const float* __restrict__ b1, const float* __restrict__ b2,
    short* __restrict__ oH0, short* __restrict__ oL0,
    short* __restrict__ oH1, short* __restrict__ oL1,
    short* __restrict__ oH2, short* __restrict__ oL2) {
    const int z = blockIdx.z;
    const short* Xh = (z == 0) ? Xh0 : (z == 1) ? Xh1 : Xh2;
    const short* Xl = (z == 0) ? Xl0 : (z == 1) ? Xl1 : Xl2;
    const short* Wh = (z == 0) ? Wh0 : (z == 1) ? Wh1 : Wh2;
    const short* Wl = (z == 0) ? Wl0 : (z == 1) ? Wl1 : Wl2;
    const float* bias = (z == 0) ? b0 : (z == 1) ? b1 : b2;
    short* outH = (z == 0) ? oH0 : (z == 1) ? oH1 : oH2;
    short* outL = (z == 0) ? oL0 : (z == 1) ? oL1 : oL2;
    const int writeLo = (z < 2);

    __shared__ __align__(16) short Ah[64 * 40], Al[64 * 40], Bh[64 * 40], Bl[64 * 40];
    const int bn = blockIdx.x * 64;
    const int bm = blockIdx.y * 64;
    const int tid = threadIdx.x;
    const int wave = tid >> 6, lane = tid & 63;
    const int m16 = lane & 15, q = lane >> 4;
    const int srow = tid >> 2, sk = (tid & 3) * 8;

    f32x4 acc[4] = {};

    for (int k0 = 0; k0 < E_DIM; k0 += 32) {
        {
            const size_t ax = (size_t)(bm + srow) * E_DIM + k0 + sk;
            const size_t bx = (size_t)(bn + srow) * E_DIM + k0 + sk;
            *(bf16x8*)&Ah[srow * 40 + sk] = *(const bf16x8*)(Xh + ax);
            *(bf16x8*)&Al[srow * 40 + sk] = *(const bf16x8*)(Xl + ax);
            *(bf16x8*)&Bh[srow * 40 + sk] = *(const bf16x8*)(Wh + bx);
            *(bf16x8*)&Bl[srow * 40 + sk] = *(const bf16x8*)(Wl + bx);
        }
        __syncthreads();
        const bf16x8 ah = *(const bf16x8*)&Ah[(wave * 16 + m16) * 40 + q * 8];
        const bf16x8 al = *(const bf16x8*)&Al[(wave * 16 + m16) * 40 + q * 8];
#pragma unroll
        for (int j = 0; j < 4; ++j) {
            const bf16x8 bh_ = *(const bf16x8*)&Bh[(j * 16 + m16) * 40 + q * 8];
            const bf16x8 bl_ = *(const bf16x8*)&Bl[(j * 16 + m16) * 40 + q * 8];
            acc[j] = MFMA(ah, bh_, acc[j]);
            acc[j] = MFMA(ah, bl_, acc[j]);
            acc[j] = MFMA(al, bh_, acc[j]);
        }
        __syncthreads();
    }

#pragma unroll
    for (int j = 0; j < 4; ++j) {
        const int e = bn + j * 16 + m16;
        const int h = e >> 6, d = e & 63;
        const float be = bias[e];
#pragma unroll
        for (int r = 0; r < 4; ++r) {
            const int row = bm + wave * 16 + q * 4 + r;
            const int l = row >> 1, nb = row & 1;
            const float v = acc[j][r] + be;
            const size_t idx = ((size_t)(h * 2 + nb) * L_SEQ + l) * D_HEAD + d;
            const short hi = f2bf(v);
            outH[idx] = hi;
            if (writeLo) outL[idx] = f2bf(v - bf2f(hi));
        }
    }
}

// ---------------------------------------------------------------------------
// V transpose (verbatim R0): Vb [bh][s][64] -> Vt [bh][64][s]
// ---------------------------------------------------------------------------
__global__ __launch_bounds__(256) void vtrans_kernel(const short* __restrict__ Vb,
                                                     short* __restrict__ Vt) {
    __shared__ short tile[64][65];
    const int s0 = blockIdx.x * 64;
    const int bh = blockIdx.y;
    const int t = threadIdx.x;
    const int r = t >> 2, seg = (t & 3) * 16;
    const bf16x8* p = (const bf16x8*)(Vb + ((size_t)bh * S_SEQ + s0 + r) * D_HEAD + seg);
    bf16x8 v0 = p[0], v1 = p[1];
#pragma unroll
    for (int i = 0; i < 8; ++i) {
        tile[r][seg + i] = v0[i];
        tile[r][seg + 8 + i] = v1[i];
    }
    __syncthreads();
    bf16x8 o0, o1;
#pragma unroll
    for (int i = 0; i < 8; ++i) {
        o0[i] = tile[seg + i][r];
        o1[i] = tile[seg + 8 + i][r];
    }
    bf16x8* po = (bf16x8*)(Vt + ((size_t)bh * D_HEAD + r) * S_SEQ + s0 + seg);
    po[0] = o0;
    po[1] = o1;
}

// ---------------------------------------------------------------------------
// Scores + bias + softmax + weights write — verbatim R12 (R0 phase-1+softmax).
// ---------------------------------------------------------------------------
__global__ __launch_bounds__(512) void scores_sm_kernel(
    const short* __restrict__ Qh, const short* __restrict__ Ql,
    const short* __restrict__ Kh, const short* __restrict__ Kl,
    const float* __restrict__ bias, float* __restrict__ wout) {
    const int bh = blockIdx.y;
    const int l0 = blockIdx.x * 16;
    const int tid = threadIdx.x;
    const int wave = tid >> 6, lane = tid & 63;
    const int m16 = lane & 15, q = lane >> 4;
    const int sbase = wave * 256;

    __shared__ float LMAX[8][16], LSUM[8][16];

    const size_t qoff = ((size_t)bh * L_SEQ + l0 + m16) * D_HEAD;
    bf16x8 aH[2], aL[2];
#pragma unroll
    for (int ks = 0; ks < 2; ++ks) {
        aH[ks] = *(const bf16x8*)(Qh + qoff + ks * 32 + q * 8);
        aL[ks] = *(const bf16x8*)(Ql + qoff + ks * 32 + q * 8);
    }

    f32x4 C[16] = {};
#pragma unroll
    for (int t = 0; t < 16; ++t) {
        const size_t koff = ((size_t)bh * S_SEQ + sbase + t * 16 + m16) * D_HEAD;
#pragma unroll
        for (int ks = 0; ks < 2; ++ks) {
            const bf16x8 kh = *(const bf16x8*)(Kh + koff + ks * 32 + q * 8);
            const bf16x8 kl = *(const bf16x8*)(Kl + koff + ks * 32 + q * 8);
            C[t] = MFMA(aH[ks], kh, C[t]);
            C[t] = MFMA(aH[ks], kl, C[t]);
            C[t] = MFMA(aL[ks], kh, C[t]);
        }
    }

    const int row0 = l0 + q * 4;
#pragma unroll
    for (int r = 0; r < 4; ++r) {
        const float* brow = bias + (size_t)(row0 + r) * S_SEQ + sbase + m16;
#pragma unroll
        for (int t = 0; t < 16; ++t) C[t][r] = C[t][r] * 0.125f + brow[t * 16];
    }

    float mx[4] = {-INFINITY, -INFINITY, -INFINITY, -INFINITY};
#pragma unroll
    for (int t = 0; t < 16; ++t)
#pragma unroll
        for (int r = 0; r < 4; ++r) mx[r] = fmaxf(mx[r], C[t][r]);
#pragma unroll
    for (int d = 1; d < 16; d <<= 1)
#pragma unroll
        for (int r = 0; r < 4; ++r) mx[r] = fmaxf(mx[r], __shfl_xor(mx[r], d, 64));
    if (m16 == 0) {
#pragma unroll
        for (int r = 0; r < 4; ++r) LMAX[wave][q * 4 + r] = mx[r];
    }
    __syncthreads();
    float M[4];
#pragma unroll
    for (int r = 0; r < 4; ++r) {
        float v = -INFINITY;
#pragma unroll
        for (int w = 0; w < 8; ++w) v = fmaxf(v, LMAX[w][q * 4 + r]);
        M[r] = v;
    }

    float sm[4] = {};
#pragma unroll
    for (int t = 0; t < 16; ++t)
#pragma unroll
        for (int r = 0; r < 4; ++r) {
            const float e = __expf(C[t][r] - M[r]);
            C[t][r] = e;
            sm[r] += e;
        }
#pragma unroll
    for (int d = 1; d < 16; d <<= 1)
#pragma unroll
        for (int r = 0; r < 4; ++r) sm[r] += __shfl_xor(sm[r], d, 64);
    if (m16 == 0) {
#pragma unroll
        for (int r = 0; r < 4; ++r) LSUM[wave][q * 4 + r] = sm[r];
    }
    __syncthreads();
#pragma unroll
    for (int r = 0; r < 4; ++r) {
        float s = 0.f;
#pragma unroll
        for (int w = 0; w < 8; ++w) s += LSUM[w][q * 4 + r];
        const float inv = 1.0f / s;
        float* orow = wout + ((size_t)bh * L_SEQ + row0 + r) * S_SEQ + sbase + m16;
#pragma unroll
        for (int t = 0; t < 16; ++t) {
            C[t][r] *= inv;
            orow[t * 16] = C[t][r];
        }
    }
}

// ---------------------------------------------------------------------------
// PV GEMM (verbatim R12): ctx = P(fp32 -> bf16) @ V. 70% HBM in R12.
// ---------------------------------------------------------------------------
__global__ __launch_bounds__(256) void pv_kernel(const float* __restrict__ P,
                                                 const short* __restrict__ Vt,
                                                 short* __restrict__ ctx) {
    const int bm = blockIdx.x * 64;
    const int bh = blockIdx.y;
    const int tid = threadIdx.x;
    const int wave = tid >> 6, lane = tid & 63;
    const int m16 = lane & 15, q = lane >> 4;

    const float* pA = P + ((size_t)bh * L_SEQ + bm + wave * 16 + m16) * S_SEQ;
    f32x4 acc[4] = {};
    for (int s0 = 0; s0 < S_SEQ; s0 += 32) {
        const float4* pa = (const float4*)(pA + s0 + q * 8);
        const bf16x8 a = cvt8_h(pa[0], pa[1]);
#pragma unroll
        for (int j = 0; j < 4; ++j) {
            const bf16x8 b = *(const bf16x8*)(Vt + ((size_t)bh * D_HEAD + j * 16 + m16) * S_SEQ +
                                              s0 + q * 8);
            acc[j] = MFMA(a, b, acc[j]);
        }
    }
    const int h = bh >> 1, n = bh & 1;
#pragma unroll
    for (int j = 0; j < 4; ++j)
#pragma unroll
        for (int r = 0; r < 4; ++r) {
            const int l = bm + wave * 16 + q * 4 + r;
            ctx[(size_t)(l * N_B + n) * E_DIM + h * D_HEAD + j * 16 + m16] = f2bf(acc[j][r]);
        }
}

// ---------------------------------------------------------------------------
// Output projection — hybrid (same verified transformation as proj): stages
// PRE-SPLIT Woh bf16 (pure 16B copies, no cvt). Structure otherwise R0.
// ---------------------------------------------------------------------------
__global__ __launch_bounds__(256) void oproj_kernel(const short* __restrict__ ctx,
                                                    const short* __restrict__ Wh,
                                                    const float* __restrict__ bias,
                                                    float* __restrict__ out) {
    __shared__ __align__(16) short Bh[64 * 40];
    const int bn = blockIdx.x * 64;
    const int bm = blockIdx.y * 64;
    const int tid = threadIdx.x;
    const int wave = tid >> 6, lane = tid & 63;
    const int m16 = lane & 15, q = lane >> 4;
    const int srow = tid >> 2, sk = (tid & 3) * 8;

    f32x4 acc[4] = {};
    for (int k0 = 0; k0 < E_DIM; k0 += 32) {
        {
            *(bf16x8*)&Bh[srow * 40 + sk] =
                *(const bf16x8*)(Wh + (size_t)(bn + srow) * E_DIM + k0 + sk);
        }
        __syncthreads();
        const bf16x8 a = *(const bf16x8*)(ctx + (size_t)(bm + wave * 16 + m16) * E_DIM + k0 + q * 8);
#pragma unroll
        for (int j = 0; j < 4; ++j) {
            const bf16x8 b = *(const bf16x8*)&Bh[(j * 16 + m16) * 40 + q * 8];
            acc[j] = MFMA(a, b, acc[j]);
        }
        __syncthreads();
    }
#pragma unroll
    for (int j = 0; j < 4; ++j) {
        const int e = bn + j * 16 + m16;
        const float be = bias[e];
#pragma unroll
        for (int r = 0; r < 4; ++r)
            out[(size_t)(bm + wave * 16 + q * 4 + r) * E_DIM + e] = acc[j][r] + be;
    }
}

extern "C" void kernel_launch(void* const* d_in, const int* in_sizes, int n_in,
                              void* d_out, int out_size, void* d_ws, size_t ws_size,
                              hipStream_t stream) {
    const float* query = (const float*)d_in[0];
    const float* key   = (const float*)d_in[1];
    const float* value = (const float*)d_in[2];
    const float* bias  = (const float*)d_in[3];
    const float* Wq    = (const float*)d_in[4];
    const float* bq    = (const float*)d_in[5];
    const float* Wk    = (const float*)d_in[6];
    const float* bk    = (const float*)d_in[7];
    const float* Wv    = (const float*)d_in[8];
    const float* bv    = (const float*)d_in[9];
    const float* Wo    = (const float*)d_in[10];
    const float* bo    = (const float*)d_in[11];

    float* out0 = (float*)d_out;                       // attn_out (L,N,E) — write-only
    float* wgt  = out0 + (size_t)M_ROWS * E_DIM;       // attn_weights (BH,L,S) fp32

    // ws: 7 x 4 MB bf16 buffers = 28 MB (verified footprint).
    short* wsS = (short*)d_ws;
    const size_t buf = (size_t)BH * L_SEQ * D_HEAD;    // 2,097,152 elems
    short* Qh  = wsS + 0 * buf;
    short* Ql  = wsS + 1 * buf;
    short* Kh  = wsS + 2 * buf;
    short* Kl  = wsS + 3 * buf;
    short* Vh  = wsS + 4 * buf;
    short* Vt  = wsS + 5 * buf;
    short* ctx = wsS + 6 * buf;

    // Split scratch: tail of the 256 MB weights output (R10/R12-verified
    // trick), 28.3 MB: 3x(Xh,Xl) + 3x(Wh,Wl). Consumed by proj3 strictly
    // BEFORE scores_sm overwrites the entire weights region.
    const size_t Xe = (size_t)M_ROWS * E_DIM;          // 2,097,152 shorts / buffer
    const size_t wb = (size_t)E_DIM * E_DIM;           // 262,144 shorts
    const size_t wgtElems = (size_t)BH * L_SEQ * S_SEQ;  // 67,108,864 floats
    const size_t totalS = 6 * Xe + 6 * wb;             // 14,155,776 shorts
    short* scr = (short*)wgt + 2 * wgtElems - totalS;
    short* Xqh = scr + 0 * Xe; short* Xql = scr + 1 * Xe;
    short* Xkh = scr + 2 * Xe; short* Xkl = scr + 3 * Xe;
    short* Xvh = scr + 4 * Xe; short* Xvl = scr + 5 * Xe;
    short* Wqh = scr + 6 * Xe;  short* Wql = Wqh + wb;
    short* Wkh = Wql + wb;      short* Wkl = Wkh + wb;
    short* Wvh = Wkl + wb;      short* Wvl = Wvh + wb;

    // Wo split goes into the dead Qh slot AFTER scores_sm.
    short* Woh = Qh;
    short* Wol = Qh + wb;

    const int nW8 = (int)(wb / 8);                     // 32768  -> 128 blocks
    const int nX8 = (int)(Xe / 8);                     // 262144 -> 1024 blocks
    const dim3 gproj3(E_DIM / 64, M_ROWS / 64, 3);     // (8, 64, 3) = 1536 blocks
    const dim3 gproj(E_DIM / 64, M_ROWS / 64);         // (8, 64) for oproj

    // Deterministic ws baseline every call (verbatim R0)
    fill_kernel<<<2048, 256, 0, stream>>>((float4*)d_ws, (int)(7 * buf * sizeof(short) / 16));

    // All splits up front (2 launches), then ONE merged projection launch.
    split3_kernel<<<dim3(nX8 / 256, 3), 256, 0, stream>>>(
        query, key, value, Xqh, Xql, Xkh, Xkl, Xvh, Xvl, nX8);
    split3_kernel<<<dim3(nW8 / 256, 3), 256, 0, stream>>>(
        Wq, Wk, Wv, Wqh, Wql, Wkh, Wkl, Wvh, Wvl, nW8);

    // V's lo is not consumed: writeLo=0 inside (z==2); dummy target never stored.
    proj_qkv3_kernel<<<gproj3, 256, 0, stream>>>(
        Xqh, Xql, Xkh, Xkl, Xvh, Xvl,
        Wqh, Wql, Wkh, Wkl, Wvh, Wvl,
        bq, bk, bv,
        Qh, Ql, Kh, Kl, Vh, (short*)wgt);

    vtrans_kernel<<<dim3(S_SEQ / 64, BH), 256, 0, stream>>>(Vh, Vt);

    scores_sm_kernel<<<dim3(L_SEQ / 16, BH), 512, 0, stream>>>(Qh, Ql, Kh, Kl, bias, wgt);

    // Qh is dead now; split Wo into it for the hybrid oproj.
    split_kernel<<<nW8 / 256, 256, 0, stream>>>(Wo, Woh, Wol, nW8);

    pv_kernel<<<dim3(L_SEQ / 64, BH), 256, 0, stream>>>(wgt, Vt, ctx);

    oproj_kernel<<<gproj, 256, 0, stream>>>(ctx, Woh, bo, out0);
}